// Round 12
// baseline (133.117 us; speedup 1.0000x reference)
//
#include <hip/hip_runtime.h>
#include <hip/hip_fp16.h>

#define B_  64
#define C_  32
#define N_  1152
#define DI_ 8
#define DC_ 16
#define NCH 3                // fallback: n's per staged chunk
#define NSLOT 128            // fallback: chunk-slots
#define STH 512
#define NOCT 24              // route n-groups (48 n each): 1536 blocks = 6/CU
#define NPW 6                // n's per wave (contiguous strip)

static __device__ __forceinline__ unsigned pkh(float a, float b) {
    __half2 t = __float22half2_rn(make_float2(a, b));
    return *reinterpret_cast<unsigned*>(&t);
}
static __device__ __forceinline__ float2 uph(unsigned u) {
    __half2 h; *reinterpret_cast<unsigned*>(&h) = u;
    return __half22float2(h);
}

// ---------------- caps_hat: n-major, barrier-free, register-held W ---------
// block = one n, 64 threads. Lane (c,h) holds its 256-B W frag in 16 float4
// REGS (64x b-amortization), X in 2 KB LDS, then a 64-b loop of pure FMA +
// one 1KB/wave coalesced hat store per b — stores flow freely (no barriers;
// R10 showed barrier-chopped stores cap at ~2 TB/s).
__global__ __launch_bounds__(64) void caps_hat(
    const float* __restrict__ X, const float* __restrict__ W,
    uint4* __restrict__ hatg)
{
    __shared__ float xl[64 * 8];             // [b][8]
    const int n    = blockIdx.x;
    const int lane = threadIdx.x;
    const int c    = lane & 31;
    const int h    = lane >> 5;

    {
        const float* xp = X + ((size_t)lane * N_ + n) * 8;
        *(float4*)(xl + lane * 8)     = *(const float4*)xp;
        *(float4*)(xl + lane * 8 + 4) = *(const float4*)(xp + 4);
    }
    float4 wr[16];
    const float* wp = W + ((size_t)c * N_ + n) * 128 + h * 64;
#pragma unroll
    for (int q = 0; q < 16; q++) wr[q] = *(const float4*)(wp + q * 4);
    __syncthreads();

    uint4* hout = hatg + (size_t)n * 64 + (2 * c + h);
#pragma unroll 4
    for (int b = 0; b < 64; b++) {
        const float4 xa = *(const float4*)(xl + b * 8);      // broadcast
        const float4 xb = *(const float4*)(xl + b * 8 + 4);
        float hv[8];
#pragma unroll
        for (int r = 0; r < 8; r++) {
            const float4 wa = wr[2 * r], wb = wr[2 * r + 1];
            hv[r] = wa.x*xa.x + wa.y*xa.y + wa.z*xa.z + wa.w*xa.w
                  + wb.x*xb.x + wb.y*xb.y + wb.z*xb.z + wb.w*xb.w;
        }
        uint4 hq;
        hq.x = pkh(hv[0], hv[1]);
        hq.y = pkh(hv[2], hv[3]);
        hq.z = pkh(hv[4], hv[5]);
        hq.w = pkh(hv[6], hv[7]);
        hout[(size_t)b * (N_ * 64)] = hq;     // hat[(b*N+n)*64 + le]
    }
}

// ---------------- caps_route: one pass over fp16 hat -----------------------
// R11 post-mortem: route ~35us/pass at ~2 TB/s, the dominant cost. Theory:
// MLP-bound — 8-wave blocks at 4/CU leave the memory pipe idle during each
// wave's serial softmax phase. This round: NOCT=24 (48 n/oct), grid 1536 =
// 6 blocks/CU (+50% resident waves), wave owns a CONTIGUOUS 6-n strip with
// all 6 loads issued upfront. mode 0: softc=1/32 (s0 pass, no softmax).
__global__ __launch_bounds__(STH, 2) void caps_route(
    const uint4* __restrict__ hatg, const float* __restrict__ accb,
    float* __restrict__ p2, int mode, float postscale)
{
    __shared__ float red[8 * 512];
    const int b    = blockIdx.x / NOCT;
    const int oct  = blockIdx.x % NOCT;
    const int tid  = threadIdx.x;
    const int w    = tid >> 6;
    const int lane = tid & 63;
    const int c    = lane & 31;
    const int h    = lane >> 5;
    const int le   = 2 * c + h;

    float4 a0 = make_float4(0.f,0.f,0.f,0.f), a1 = a0;
    if (mode) {
        const float* ap = accb + (size_t)b * 512 + le * 8;
        a0 = *(const float4*)ap;
        a1 = *(const float4*)(ap + 4);
    }

    // wave's contiguous strip: n = oct*48 + w*6 + idx
    const uint4* hb = hatg + ((size_t)b * N_ + oct * 48 + w * NPW) * 64 + le;
    uint4 v[NPW];
#pragma unroll
    for (int idx = 0; idx < NPW; idx++)
        v[idx] = hb[(size_t)idx * 64];

    float acc[8] = {0.f,0.f,0.f,0.f,0.f,0.f,0.f,0.f};
#pragma unroll
    for (int idx = 0; idx < NPW; idx++) {
        const float2 f0 = uph(v[idx].x);
        const float2 f1 = uph(v[idx].y);
        const float2 f2 = uph(v[idx].z);
        const float2 f3 = uph(v[idx].w);
        float sc;
        if (mode) {
            float lg = f0.x*a0.x + f0.y*a0.y + f1.x*a0.z + f1.y*a0.w
                     + f2.x*a1.x + f2.y*a1.y + f3.x*a1.z + f3.y*a1.w;
            lg += __shfl_xor(lg, 32, 64);            // combine i-halves (same c)
            const float e = __expf(lg);              // no max-subtract: |lg| small
            float s = e;
#pragma unroll
            for (int m = 16; m >= 1; m >>= 1) s += __shfl_xor(s, m, 64);
            sc = e * __builtin_amdgcn_rcpf(s);
        } else {
            sc = 1.0f;                               // 1/32 folded via postscale
        }
        acc[0] += sc * f0.x; acc[1] += sc * f0.y;
        acc[2] += sc * f1.x; acc[3] += sc * f1.y;
        acc[4] += sc * f2.x; acc[5] += sc * f2.y;
        acc[6] += sc * f3.x; acc[7] += sc * f3.y;
    }

    // block reduce over 8 waves
    *(float4*)(red + w * 512 + le * 8)     = make_float4(acc[0], acc[1], acc[2], acc[3]);
    *(float4*)(red + w * 512 + le * 8 + 4) = make_float4(acc[4], acc[5], acc[6], acc[7]);
    __syncthreads();
    float vs = 0.f;
#pragma unroll
    for (int s = 0; s < 8; s++) vs += red[s * 512 + tid];
    p2[(size_t)(b * NOCT + oct) * 512 + tid] = vs * postscale;
}

// ---------------- caps_r2: reduce NOCT oct-slabs per b, squash -------------
__global__ __launch_bounds__(512) void caps_r2(
    const float* __restrict__ p2, float* __restrict__ accb,
    float* __restrict__ out, int t)
{
    const int b = blockIdx.x;
    const int e = threadIdx.x;               // [c=e>>4][i=e&15]
    const float* base = p2 + (size_t)b * (NOCT * 512) + e;
    float v = 0.f;
#pragma unroll
    for (int s = 0; s < NOCT; s++) v += base[s * 512];
    float sq = v * v;
#pragma unroll
    for (int m = 1; m <= 8; m <<= 1) sq += __shfl_xor(sq, m, 64);  // sum over i
    const float scale = sq / (1.f + sq) * rsqrtf(sq + 1e-7f);
    const float ov = v * scale;
    const int oidx = b * 512 + e;
    if (t == 2)      out[oidx]  = ov;
    else if (t == 0) accb[oidx] = ov;        // accb starts poisoned: write, not +=
    else             accb[oidx] += ov;
}

// ---------------- fallback (R5 path, 16.9 MB ws) ---------------------------
__global__ __launch_bounds__(STH, 2) void caps_s_fb(
    const float* __restrict__ X, const float* __restrict__ W,
    const float* __restrict__ aout, float* __restrict__ partials, int t)
{
    __shared__ float wlds[NCH * 64 * 64];
    __shared__ float xlds[NCH * 16 * 8];
    const int bg = blockIdx.x & 3, slot = blockIdx.x >> 2;
    const int tid = threadIdx.x, w = tid >> 6, lane = tid & 63;
    const int c = lane & 31, h = lane >> 5, bl0 = w * 2, sw = c & 7;
    float areg[2][8] = {};
    if (t > 0) {
#pragma unroll
        for (int bq = 0; bq < 2; bq++) {
            const float* ap = aout + (size_t)(bg * 16 + bl0 + bq) * 512 + c * 16 + h * 8;
            const float4 a0 = *(const float4*)ap; const float4 a1 = *(const float4*)(ap + 4);
            areg[bq][0]=a0.x; areg[bq][1]=a0.y; areg[bq][2]=a0.z; areg[bq][3]=a0.w;
            areg[bq][4]=a1.x; areg[bq][5]=a1.y; areg[bq][6]=a1.z; areg[bq][7]=a1.w;
        }
    }
    float acc[2][8];
#pragma unroll
    for (int bq = 0; bq < 2; bq++)
#pragma unroll
        for (int r = 0; r < 8; r++) acc[bq][r] = 0.f;
    for (int cc = 0; cc < 3; cc++) {
        if (cc) __syncthreads();
        const int n0 = (slot + cc * NSLOT) * NCH;
        for (int G = tid; G < NCH * 1024; G += STH) {
            const int nl = G >> 10, f = (G >> 4) & 63, q = G & 15;
            const int wc = f >> 1, wh = f & 1;
            const float4 v = *(const float4*)(W + (size_t)(wc * N_ + n0 + nl) * 128 + wh * 64 + q * 4);
            *(float4*)(wlds + (nl * 64 + f) * 64 + (q ^ (wc & 7)) * 4) = v;
        }
        if (tid < NCH * 32) {
            const int nl = tid >> 5, bl = (tid >> 1) & 15, qx = tid & 1;
            const float4 v = *(const float4*)(X + (size_t)((bg * 16 + bl) * N_ + n0 + nl) * DI_ + qx * 4);
            *(float4*)(xlds + (nl * 16 + bl) * 8 + qx * 4) = v;
        }
        __syncthreads();
#pragma unroll
        for (int nl = 0; nl < NCH; nl++) {
            float4 xa[2], xb[2];
#pragma unroll
            for (int bq = 0; bq < 2; bq++) {
                const float* xp = xlds + (nl * 16 + bl0 + bq) * 8;
                xa[bq] = *(const float4*)xp; xb[bq] = *(const float4*)(xp + 4);
            }
            float hat[2][8];
            const float* frag = wlds + (nl * 64 + 2 * c + h) * 64;
#pragma unroll
            for (int r = 0; r < 8; r++) {
                const int pa = ((2 * r) ^ sw) * 4; const int pb = pa ^ 4;
                const float4 wa = *(const float4*)(frag + pa);
                const float4 wb = *(const float4*)(frag + pb);
#pragma unroll
                for (int bq = 0; bq < 2; bq++)
                    hat[bq][r] = wa.x*xa[bq].x + wa.y*xa[bq].y + wa.z*xa[bq].z + wa.w*xa[bq].w
                               + wb.x*xb[bq].x + wb.y*xb[bq].y + wb.z*xb[bq].z + wb.w*xb[bq].w;
            }
#pragma unroll
            for (int bq = 0; bq < 2; bq++) {
                float softc;
                if (t > 0) {
                    float lg = hat[bq][0]*areg[bq][0] + hat[bq][1]*areg[bq][1]
                             + hat[bq][2]*areg[bq][2] + hat[bq][3]*areg[bq][3]
                             + hat[bq][4]*areg[bq][4] + hat[bq][5]*areg[bq][5]
                             + hat[bq][6]*areg[bq][6] + hat[bq][7]*areg[bq][7];
                    lg += __shfl_xor(lg, 32, 64);
                    const float e = __expf(lg);
                    float s = e;
#pragma unroll
                    for (int m = 16; m >= 1; m >>= 1) s += __shfl_xor(s, m, 64);
                    softc = e / s;
                } else softc = 1.0f / 32.0f;
#pragma unroll
                for (int r = 0; r < 8; r++) acc[bq][r] += softc * hat[bq][r];
            }
        }
    }
    float* pout = partials + (size_t)(bg * NSLOT + slot) * 8192;
#pragma unroll
    for (int bq = 0; bq < 2; bq++) {
        float* pb = pout + (bl0 + bq) * 512 + c * 16 + h * 8;
        *(float4*)pb       = make_float4(acc[bq][0], acc[bq][1], acc[bq][2], acc[bq][3]);
        *(float4*)(pb + 4) = make_float4(acc[bq][4], acc[bq][5], acc[bq][6], acc[bq][7]);
    }
}

__global__ __launch_bounds__(256) void caps_r1_fb(
    const float* __restrict__ p1, float* __restrict__ accb,
    float* __restrict__ out, int t)
{
    const int b   = blockIdx.x >> 2;
    const int q   = blockIdx.x & 3;
    const int tid = threadIdx.x;
    const int e   = q * 128 + (tid >> 1);
    const int p   = tid & 1;
    const int bg  = b >> 4, bl = b & 15;
    const float* base = p1 + (size_t)bg * NSLOT * 8192 + (size_t)bl * 512 + e;
    float v = 0.f;
#pragma unroll 8
    for (int ch = p; ch < NSLOT; ch += 2)
        v += base[(size_t)ch * 8192];
    v += __shfl_xor(v, 1, 64);
    float sq = v * v;
#pragma unroll
    for (int m = 2; m <= 16; m <<= 1) sq += __shfl_xor(sq, m, 64);
    const float scale = sq / (1.f + sq) * rsqrtf(sq + 1e-7f);
    const float ov = v * scale;
    if (p == 0) {
        const int oidx = b * 512 + e;
        if (t == 2) out[oidx] = ov;
        else        accb[oidx] = (t == 0) ? ov : (accb[oidx] + ov);
    }
}

extern "C" void kernel_launch(void* const* d_in, const int* in_sizes, int n_in,
                              void* d_out, int out_size, void* d_ws, size_t ws_size,
                              hipStream_t stream) {
    const float* X = (const float*)d_in[0];   // [B,N,DI]
    const float* W = (const float*)d_in[1];   // [C,N,DC,DI]
    float* out = (float*)d_out;               // [B,C,DC]

    const size_t hat_b = (size_t)B_ * N_ * 512 * 2;      // 75,497,472 (fp16)
    const size_t p2_b  = (size_t)B_ * NOCT * 512 * 4;    //  3,145,728
    const size_t acc_b = (size_t)B_ * 512 * 4;           //    131,072

    if (ws_size >= hat_b + p2_b + acc_b) {
        char* ws = (char*)d_ws;
        uint4* hatg = (uint4*)ws;
        float* p2   = (float*)(ws + hat_b);
        float* accb = (float*)(ws + hat_b + p2_b);
        caps_hat  <<<N_, 64, 0, stream>>>(X, W, hatg);
        caps_route<<<B_ * NOCT, STH, 0, stream>>>(hatg, accb, p2, 0, 0.03125f);
        caps_r2   <<<B_, 512, 0, stream>>>(p2, accb, out, 0);
        caps_route<<<B_ * NOCT, STH, 0, stream>>>(hatg, accb, p2, 1, 1.0f);
        caps_r2   <<<B_, 512, 0, stream>>>(p2, accb, out, 1);
        caps_route<<<B_ * NOCT, STH, 0, stream>>>(hatg, accb, p2, 1, 1.0f);
        caps_r2   <<<B_, 512, 0, stream>>>(p2, accb, out, 2);
    } else {
        float* p1 = (float*)d_ws;             // 16.8 MB
        float* accb = p1 + (size_t)512 * 8192;
        for (int t = 0; t < 3; t++) {
            caps_s_fb<<<512, STH, 0, stream>>>(X, W, accb, p1, t);
            caps_r1_fb<<<256, 256, 0, stream>>>(p1, accb, out, t);
        }
    }
}